// Round 3
// baseline (256.028 us; speedup 1.0000x reference)
//
#include <hip/hip_runtime.h>
#include <hip/hip_bf16.h>
#include <hip/hip_fp16.h>

#define HW      262144   // 512*512 spatial positions (P)
#define NCH     128      // channels (GEMM K)
#define NCLS    128      // classes  (GEMM N)
#define KROWS   131072   // gathered rows
#define BM      64       // positions per tile
#define OLP     144      // Ol pitch in halfs: 288 B/row, conflict-free transpose

typedef short  bf16x8 __attribute__((ext_vector_type(8)));
typedef float  f32x4  __attribute__((ext_vector_type(4)));

__device__ inline ushort f2bf(float f) {
    union { float f; unsigned u; } v; v.f = f;
    unsigned u = v.u;
    unsigned r = (u + 0x7FFFu + ((u >> 16) & 1u)) >> 16;   // RNE
    return (ushort)r;
}

// ---------------- CSR inverse-map construction ----------------

__global__ __launch_bounds__(256) void csr_zero(int4* __restrict__ cnt4) {
    cnt4[blockIdx.x * 256 + threadIdx.x] = make_int4(0, 0, 0, 0);
}

__global__ __launch_bounds__(256) void csr_hist(const int* __restrict__ idx,
                                                int* __restrict__ cnt) {
    int k = blockIdx.x * 256 + threadIdx.x;
    atomicAdd(&cnt[idx[k]], 1);
}

// per-block exclusive scan of 256 counts; block total -> bsum
__global__ __launch_bounds__(256) void scan_a(const int* __restrict__ cnt,
                                              int* __restrict__ off,
                                              int* __restrict__ bsum) {
    __shared__ int s[256];
    const int t = threadIdx.x;
    const int base = blockIdx.x * 256;
    int v = cnt[base + t];
    s[t] = v;
    __syncthreads();
    #pragma unroll
    for (int o = 1; o < 256; o <<= 1) {
        int add = (t >= o) ? s[t - o] : 0;
        __syncthreads();
        s[t] += add;
        __syncthreads();
    }
    off[base + t] = s[t] - v;            // exclusive
    if (t == 255) bsum[blockIdx.x] = s[255];
}

// single block: exclusive scan of the 1024 block sums (in place)
__global__ __launch_bounds__(256) void scan_b(int* __restrict__ bsum) {
    __shared__ int s[256];
    const int t = threadIdx.x;
    int4 v = ((int4*)bsum)[t];
    int sum4 = v.x + v.y + v.z + v.w;
    s[t] = sum4;
    __syncthreads();
    #pragma unroll
    for (int o = 1; o < 256; o <<= 1) {
        int add = (t >= o) ? s[t - o] : 0;
        __syncthreads();
        s[t] += add;
        __syncthreads();
    }
    int base = s[t] - sum4;
    int4 o;
    o.x = base;
    o.y = base + v.x;
    o.z = base + v.x + v.y;
    o.w = base + v.x + v.y + v.z;
    ((int4*)bsum)[t] = o;
}

// add scanned block offsets; duplicate into cursor array; cap off[P]
__global__ __launch_bounds__(256) void scan_c(int* __restrict__ off,
                                              int* __restrict__ cur,
                                              const int* __restrict__ bsum) {
    const int i = blockIdx.x * 256 + threadIdx.x;
    int o = off[i] + bsum[blockIdx.x];
    off[i] = o;
    cur[i] = o;
    if (i == 0) off[HW] = KROWS;
}

__global__ __launch_bounds__(256) void csr_fill(const int* __restrict__ idx,
                                                int* __restrict__ cur,
                                                int* __restrict__ list) {
    int k = blockIdx.x * 256 + threadIdx.x;
    int p = idx[k];
    int pos = atomicAdd(&cur[p], 1);
    list[pos] = k;
}

// ---------------- W pre-swizzle (fp32 -> bf16 fragment order) ----------------
__global__ __launch_bounds__(256) void wconv(const float* __restrict__ Wc,
                                             ushort* __restrict__ Wf) {
    int e    = blockIdx.x * 256 + threadIdx.x;   // 0..16383
    int j    = e & 7;
    int slot = e >> 3;
    int lane = slot & 63;
    int kk   = (slot >> 6) & 3;
    int nt   = slot >> 8;
    int n = (nt << 4) + (lane & 15);
    int k = (kk << 5) + ((lane >> 4) << 3) + j;
    Wf[e] = f2bf(Wc[n * NCH + k]);
}

// ---------------- fused GEMM + softmax + CSR scatter ----------------
__global__ __launch_bounds__(256) void gemm_scatter(const float* __restrict__ gc,
                                                    const ushort* __restrict__ Wf,
                                                    const float* __restrict__ bias,
                                                    const int* __restrict__ off,
                                                    const int* __restrict__ list,
                                                    float* __restrict__ out) {
    __shared__ ushort Wl[NCLS * NCH];   // 32 KiB, fragment-ordered
    __shared__ ushort AO[BM * OLP];     // 18432 B: A-frags, then fp16 prob transpose

    const int t    = threadIdx.x;
    const int lane = t & 63;
    const int wv   = t >> 6;
    const int l15  = lane & 15;

    // stage W: 16B-per-lane async copy
    #pragma unroll
    for (int i = 0; i < 8; ++i) {
        const ushort* g = Wf + (i << 11) + (t << 3);
        ushort*       l = Wl + (i << 11) + (t << 3);
        __builtin_amdgcn_global_load_lds(
            (const __attribute__((address_space(1))) unsigned*)g,
            (__attribute__((address_space(3))) unsigned*)l, 16, 0, 0);
    }

    float bcol[8];
    #pragma unroll
    for (int nt = 0; nt < 8; ++nt) bcol[nt] = bias[(nt << 4) + l15];

    for (int tile = 0; tile < 2; ++tile) {
        const int m0 = (blockIdx.x * 2 + tile) * BM;

        __syncthreads();   // W ready (iter0) / prior tile's AO scatter reads done

        // stage A tile (64 m x 128 c) as A-fragments
        #pragma unroll
        for (int i = 0; i < 4; ++i) {
            int q  = (i << 8) + t;
            int cp = q >> 4;
            int mq = q & 15;
            int c0 = cp << 1;
            int m  = mq << 2;
            float4 v0 = *(const float4*)&gc[(size_t)c0 * HW + m0 + m];
            float4 v1 = *(const float4*)&gc[(size_t)(c0 + 1) * HW + m0 + m];
            int kk = c0 >> 5;
            int hi = ((c0 >> 3) & 3) << 4;
            int j  = c0 & 7;
            const float* a0 = (const float*)&v0;
            const float* a1 = (const float*)&v1;
            #pragma unroll
            for (int d = 0; d < 4; ++d) {
                int row   = m + d;
                int lslot = (row & 15) + hi;
                int mt    = row >> 4;
                int addr  = ((((mt << 2) + kk) << 6) + lslot) << 3;
                __hip_bfloat162 pk = __float22bfloat162_rn(make_float2(a0[d], a1[d]));
                *(ushort2*)&AO[addr + j] = *(ushort2*)&pk;
            }
        }
        __syncthreads();

        // MFMA: wave wv owns 16 rows x 128 cols
        f32x4 acc[8];
        #pragma unroll
        for (int i = 0; i < 8; ++i) acc[i] = (f32x4){0.f, 0.f, 0.f, 0.f};

        #pragma unroll
        for (int kk = 0; kk < 4; ++kk) {
            bf16x8 a = *(const bf16x8*)&AO[((((wv << 2) + kk) << 6) + lane) << 3];
            #pragma unroll
            for (int nt = 0; nt < 8; ++nt) {
                bf16x8 b = *(const bf16x8*)&Wl[((((nt << 2) + kk) << 6) + lane) << 3];
                acc[nt] = __builtin_amdgcn_mfma_f32_16x16x32_bf16(a, b, acc[nt], 0, 0, 0);
            }
        }

        // fused softmax in registers
        float pr[8][4];
        #pragma unroll
        for (int rr = 0; rr < 4; ++rr) {
            float ex[8], s = 0.f;
            #pragma unroll
            for (int nt = 0; nt < 8; ++nt) {
                ex[nt] = __expf(acc[nt][rr] + bcol[nt]);
                s += ex[nt];
            }
            s += __shfl_xor(s, 1, 64);
            s += __shfl_xor(s, 2, 64);
            s += __shfl_xor(s, 4, 64);
            s += __shfl_xor(s, 8, 64);
            float inv = 1.0f / s;
            #pragma unroll
            for (int nt = 0; nt < 8; ++nt) pr[nt][rr] = ex[nt] * inv;
        }

        __syncthreads();   // all MFMA reads of AO done -> safe to overwrite

        // transpose probs (fp16) through LDS
        const int rowb = (wv << 4) + ((lane >> 4) << 2);
        #pragma unroll
        for (int nt = 0; nt < 8; ++nt)
            #pragma unroll
            for (int rr = 0; rr < 4; ++rr)
                AO[(rowb + rr) * OLP + (nt << 4) + l15] =
                    __half_as_ushort(__float2half_rn(pr[nt][rr]));
        __syncthreads();

        // CSR scatter: wave wv owns rows wv*16 .. wv*16+15 (contiguous p range)
        const int pbase = m0 + (wv << 4);
        int ofl = 0;
        if (lane < 17) ofl = off[pbase + lane];

        #pragma unroll 1
        for (int r = 0; r < 16; ++r) {
            int o0 = __shfl(ofl, r, 64);
            int o1 = __shfl(ofl, r + 1, 64);
            if (o0 == o1) continue;
            __half2 h = *(const __half2*)&AO[((wv << 4) + r) * OLP + (lane << 1)];
            float2 f = __half22float2(h);
            #pragma unroll 1
            for (int e = o0; e < o1; ++e) {
                int k = list[e];
                *(float2*)&out[(size_t)k * NCLS + (lane << 1)] = f;
            }
        }
    }
}

extern "C" void kernel_launch(void* const* d_in, const int* in_sizes, int n_in,
                              void* d_out, int out_size, void* d_ws, size_t ws_size,
                              hipStream_t stream) {
    const float* gc   = (const float*)d_in[0];   // [1,128,512,512] fp32
    const int*   idx  = (const int*)d_in[1];     // [1,131072] int32
    const float* Wc   = (const float*)d_in[2];   // [128,128] fp32
    const float* bias = (const float*)d_in[3];   // [128] fp32
    float* out = (float*)d_out;                  // [131072,128] fp32

    char* ws = (char*)d_ws;
    int*    cnt  = (int*)(ws);                   // P ints        (1 MiB)
    int*    off  = (int*)(ws + 0x100000);        // P+1 ints
    int*    cur  = (int*)(ws + 0x300000);        // P ints
    int*    list = (int*)(ws + 0x400000);        // K ints        (512 KiB)
    int*    bsum = (int*)(ws + 0x480000);        // 1024 ints
    ushort* Wf   = (ushort*)(ws + 0x500000);     // 16384 bf16    (32 KiB)

    csr_zero<<<dim3(256),  dim3(256), 0, stream>>>((int4*)cnt);
    csr_hist<<<dim3(512),  dim3(256), 0, stream>>>(idx, cnt);
    scan_a  <<<dim3(1024), dim3(256), 0, stream>>>(cnt, off, bsum);
    scan_b  <<<dim3(1),    dim3(256), 0, stream>>>(bsum);
    scan_c  <<<dim3(1024), dim3(256), 0, stream>>>(off, cur, bsum);
    csr_fill<<<dim3(512),  dim3(256), 0, stream>>>(idx, cur, list);
    wconv   <<<dim3(64),   dim3(256), 0, stream>>>(Wc, Wf);
    gemm_scatter<<<dim3(HW / (2 * BM)), dim3(256), 0, stream>>>(gc, Wf, bias, off, list, out);
}

// Round 4
// 241.185 us; speedup vs baseline: 1.0615x; 1.0615x over previous
//
#include <hip/hip_runtime.h>
#include <hip/hip_bf16.h>
#include <hip/hip_fp16.h>

#define HW      262144   // 512*512 spatial positions
#define NCH     128      // channels (GEMM K)
#define NCLS    128      // classes  (GEMM N)
#define KROWS   131072   // gathered rows

typedef short  bf16x8 __attribute__((ext_vector_type(8)));
typedef float  f32x4  __attribute__((ext_vector_type(4)));

__device__ inline ushort f2bf(float f) {
    union { float f; unsigned u; } v; v.f = f;
    unsigned u = v.u;
    unsigned r = (u + 0x7FFFu + ((u >> 16) & 1u)) >> 16;   // RNE
    return (ushort)r;
}

// W fp32 -> bf16 in MFMA B-fragment order:
//   Wf[((nt*4+kk)*64 + lane)*8 + j] = bf16( W[nt*16+(lane&15)][kk*32+(lane>>4)*8+j] )
__global__ __launch_bounds__(256) void wconv(const float* __restrict__ Wc,
                                             ushort* __restrict__ Wf) {
    int e    = blockIdx.x * 256 + threadIdx.x;   // 0..16383
    int j    = e & 7;
    int slot = e >> 3;
    int lane = slot & 63;
    int kk   = (slot >> 6) & 3;
    int nt   = slot >> 8;
    int n = (nt << 4) + (lane & 15);
    int k = (kk << 5) + ((lane >> 4) << 3) + j;
    Wf[e] = f2bf(Wc[n * NCH + k]);
}

// pred16[p][n] = softmax_n( sum_c gc[c][p]*W[n][c] + b[n] )  stored fp16
// One 64-position tile per block; loads all issued up-front; 2 barriers total.
__global__ __launch_bounds__(256) void gemm_probs(const float* __restrict__ gc,
                                                  const ushort* __restrict__ Wf,
                                                  const float* __restrict__ bias,
                                                  ushort* __restrict__ pred) {
    __shared__ ushort Wl[NCLS * NCH];   // 32 KiB, fragment-ordered
    __shared__ ushort AO[64 * NCH];     // 16 KiB: A-frags, then fp16 prob transpose

    const int t    = threadIdx.x;
    const int lane = t & 63;
    const int wv   = t >> 6;
    const int l15  = lane & 15;
    const int quad = lane >> 4;
    const int m0   = blockIdx.x << 6;

    // ---- issue all A-tile loads first (max MLP, consumed at the barrier)
    float4 va[8];
    #pragma unroll
    for (int i = 0; i < 4; ++i) {
        int q  = (i << 8) + t;
        int cp = q >> 4, mq = q & 15;
        int c0 = cp << 1, m = mq << 2;
        va[2 * i]     = *(const float4*)&gc[(size_t)c0 * HW + m0 + m];
        va[2 * i + 1] = *(const float4*)&gc[(size_t)(c0 + 1) * HW + m0 + m];
    }

    // ---- W async to LDS (L2-resident after first blocks)
    #pragma unroll
    for (int i = 0; i < 8; ++i) {
        const ushort* g = Wf + (i << 11) + (t << 3);
        ushort*       l = Wl + (i << 11) + (t << 3);
        __builtin_amdgcn_global_load_lds(
            (const __attribute__((address_space(1))) unsigned*)g,
            (__attribute__((address_space(3))) unsigned*)l, 16, 0, 0);
    }

    float bcol[8];
    #pragma unroll
    for (int nt = 0; nt < 8; ++nt) bcol[nt] = bias[(nt << 4) + l15];

    // ---- convert + write A-fragments, slot XOR-swizzled by (m>>2)&7 (bank-spread)
    #pragma unroll
    for (int i = 0; i < 4; ++i) {
        int q  = (i << 8) + t;
        int cp = q >> 4, mq = q & 15;
        int c0 = cp << 1, m = mq << 2;
        int kk = c0 >> 5, kc2 = (c0 >> 3) & 3, j = c0 & 7;
        const float* a0 = (const float*)&va[2 * i];
        const float* a1 = (const float*)&va[2 * i + 1];
        #pragma unroll
        for (int d = 0; d < 4; ++d) {
            int row  = m + d;
            int slot = ((((row >> 4) << 2) + kk) << 6) + (row & 15) + (kc2 << 4);
            slot ^= (row >> 2) & 7;
            __hip_bfloat162 pk = __float22bfloat162_rn(make_float2(a0[d], a1[d]));
            *(ushort2*)&AO[(slot << 3) + j] = *(ushort2*)&pk;
        }
    }
    __syncthreads();   // A + W ready

    // ---- MFMA: wave wv owns 16 rows x 128 cols, K=128 in 4 steps
    f32x4 acc[8];
    #pragma unroll
    for (int i = 0; i < 8; ++i) acc[i] = (f32x4){0.f, 0.f, 0.f, 0.f};

    #pragma unroll
    for (int kk = 0; kk < 4; ++kk) {
        int aslot = ((((wv << 2) + kk) << 6) + lane) ^ ((((wv << 4) + l15) >> 2) & 7);
        bf16x8 a = *(const bf16x8*)&AO[aslot << 3];
        #pragma unroll
        for (int nt = 0; nt < 8; ++nt) {
            bf16x8 b = *(const bf16x8*)&Wl[((((nt << 2) + kk) << 6) + lane) << 3];
            acc[nt] = __builtin_amdgcn_mfma_f32_16x16x32_bf16(a, b, acc[nt], 0, 0, 0);
        }
    }

    // ---- softmax in place (C/D layout: col=l15+nt*16, row=quad*4+rr)
    float inv[4];
    #pragma unroll
    for (int rr = 0; rr < 4; ++rr) {
        float s = 0.f;
        #pragma unroll
        for (int nt = 0; nt < 8; ++nt) {
            acc[nt][rr] = __expf(acc[nt][rr] + bcol[nt]);
            s += acc[nt][rr];
        }
        s += __shfl_xor(s, 1, 64);
        s += __shfl_xor(s, 2, 64);
        s += __shfl_xor(s, 4, 64);
        s += __shfl_xor(s, 8, 64);
        inv[rr] = 1.0f / s;
    }

    // ---- transpose probs (fp16) into the wave's OWN A region (no barrier needed):
    // chunk swizzle g(quad) = ((quad&1)<<2)|(quad&2) — distinct mod 8 for all quads
    const int g = ((quad & 1) << 2) | (quad & 2);
    #pragma unroll
    for (int nt = 0; nt < 8; ++nt) {
        int cl = ((nt << 1) + (l15 >> 3)) ^ g;
        #pragma unroll
        for (int rr = 0; rr < 4; ++rr) {
            int row = (wv << 4) + (quad << 2) + rr;
            AO[(row << 7) + (cl << 3) + (l15 & 7)] =
                __half_as_ushort(__float2half_rn(acc[nt][rr] * inv[rr]));
        }
    }
    __syncthreads();   // probs visible

    // ---- fully-coalesced dwordx4 stores
    #pragma unroll
    for (int i = 0; i < 4; ++i) {
        int q   = (i << 8) + t;
        int row = q >> 4, ch = q & 15;
        int qd  = (row >> 2) & 3;
        int cl  = ch ^ (((qd & 1) << 2) | (qd & 2));
        int4 v = *(const int4*)&AO[(row << 7) + (cl << 3)];
        *(int4*)&pred[((size_t)(m0 + row) << 7) + (ch << 3)] = v;
    }
}

// out[k][:] = fp32( pred16[idx[k]][:] ) — 8 rows per wave for load MLP
__global__ __launch_bounds__(256) void gather_rows(const ushort* __restrict__ pred,
                                                   const int* __restrict__ idx,
                                                   float* __restrict__ out) {
    const int t    = threadIdx.x;
    const int lane = t & 63;
    const int wv   = t >> 6;
    const int kbase = (blockIdx.x << 5) + (wv << 3);

    int p[8];
    #pragma unroll
    for (int r = 0; r < 8; ++r) p[r] = idx[kbase + r];

    #pragma unroll
    for (int r = 0; r < 8; ++r) {
        __half2 h = *(const __half2*)&pred[((size_t)p[r] << 7) + (lane << 1)];
        float2 f = __half22float2(h);
        *(float2*)&out[((size_t)(kbase + r) << 7) + (lane << 1)] = f;
    }
}

extern "C" void kernel_launch(void* const* d_in, const int* in_sizes, int n_in,
                              void* d_out, int out_size, void* d_ws, size_t ws_size,
                              hipStream_t stream) {
    const float* gc   = (const float*)d_in[0];   // [1,128,512,512] fp32
    const int*   idx  = (const int*)d_in[1];     // [1,131072] int32
    const float* Wc   = (const float*)d_in[2];   // [128,128] fp32
    const float* bias = (const float*)d_in[3];   // [128] fp32
    float*  out  = (float*)d_out;                // [131072,128] fp32
    ushort* pred = (ushort*)d_ws;                // [262144,128] fp16 probs = 64 MiB
    ushort* Wf   = (ushort*)((char*)d_ws + (size_t)64 * 1024 * 1024);  // 32 KiB scratch

    wconv      <<<dim3(64),    dim3(256), 0, stream>>>(Wc, Wf);
    gemm_probs <<<dim3(HW/64), dim3(256), 0, stream>>>(gc, Wf, bias, pred);
    gather_rows<<<dim3(KROWS/32), dim3(256), 0, stream>>>(pred, idx, out);
}

// Round 5
// 236.229 us; speedup vs baseline: 1.0838x; 1.0210x over previous
//
#include <hip/hip_runtime.h>
#include <hip/hip_bf16.h>
#include <hip/hip_fp16.h>

#define HW      262144   // 512*512 spatial positions
#define NCH     128      // channels (GEMM K)
#define NCLS    128      // classes  (GEMM N)
#define KROWS   131072   // gathered rows
#define NTILE   4096     // HW / 64
#define CAP     192      // entries per tile bucket (Poisson mean 32; P(>192) ~ 0)

typedef short  bf16x8 __attribute__((ext_vector_type(8)));
typedef float  f32x4  __attribute__((ext_vector_type(4)));

__device__ inline ushort f2bf(float f) {
    union { float f; unsigned u; } v; v.f = f;
    unsigned u = v.u;
    unsigned r = (u + 0x7FFFu + ((u >> 16) & 1u)) >> 16;   // RNE
    return (ushort)r;
}

// blocks 0..63: W fp32 -> bf16 in MFMA B-fragment order
//   Wf[((nt*4+kk)*64 + lane)*8 + j] = bf16( W[nt*16+(lane&15)][kk*32+(lane>>4)*8+j] )
// blocks 64..67: zero the 4096-int tile-count array
__global__ __launch_bounds__(256) void prep(const float* __restrict__ Wc,
                                            ushort* __restrict__ Wf,
                                            int4* __restrict__ cnt4) {
    if (blockIdx.x < 64) {
        int e    = blockIdx.x * 256 + threadIdx.x;   // 0..16383
        int j    = e & 7;
        int slot = e >> 3;
        int lane = slot & 63;
        int kk   = (slot >> 6) & 3;
        int nt   = slot >> 8;
        int n = (nt << 4) + (lane & 15);
        int k = (kk << 5) + ((lane >> 4) << 3) + j;
        Wf[e] = f2bf(Wc[n * NCH + k]);
    } else {
        cnt4[(blockIdx.x - 64) * 256 + threadIdx.x] = make_int4(0, 0, 0, 0);
    }
}

// bucket each output row k by its source tile p>>6; entry packs (k<<6)|(p&63)
__global__ __launch_bounds__(256) void csr_fill(const int* __restrict__ idx,
                                                int* __restrict__ cnt,
                                                int* __restrict__ pairs) {
    int k = blockIdx.x * 256 + threadIdx.x;
    int p = idx[k];
    int tile = p >> 6;
    int pos = atomicAdd(&cnt[tile], 1);
    if (pos < CAP) pairs[tile * CAP + pos] = (k << 6) | (p & 63);
}

// logits = gc^T @ W^T + b  ->  softmax  ->  scatter rows straight to out[k]
__global__ __launch_bounds__(256) void gemm_scatter(const float* __restrict__ gc,
                                                    const ushort* __restrict__ Wf,
                                                    const float* __restrict__ bias,
                                                    const int* __restrict__ cnt,
                                                    const int* __restrict__ pairs,
                                                    float* __restrict__ out) {
    __shared__ ushort Wl[NCLS * NCH];   // 32 KiB, fragment-ordered
    __shared__ ushort AO[64 * NCH];     // 16 KiB: A-frags, then fp16 prob transpose

    const int t    = threadIdx.x;
    const int lane = t & 63;
    const int wv   = t >> 6;
    const int l15  = lane & 15;
    const int quad = lane >> 4;
    const int m0   = blockIdx.x << 6;

    // ---- issue all A-tile loads first (max MLP)
    float4 va[8];
    #pragma unroll
    for (int i = 0; i < 4; ++i) {
        int q  = (i << 8) + t;
        int cp = q >> 4, mq = q & 15;
        int c0 = cp << 1, m = mq << 2;
        va[2 * i]     = *(const float4*)&gc[(size_t)c0 * HW + m0 + m];
        va[2 * i + 1] = *(const float4*)&gc[(size_t)(c0 + 1) * HW + m0 + m];
    }

    // ---- W async to LDS (L2-resident)
    #pragma unroll
    for (int i = 0; i < 8; ++i) {
        const ushort* g = Wf + (i << 11) + (t << 3);
        ushort*       l = Wl + (i << 11) + (t << 3);
        __builtin_amdgcn_global_load_lds(
            (const __attribute__((address_space(1))) unsigned*)g,
            (__attribute__((address_space(3))) unsigned*)l, 16, 0, 0);
    }

    float bcol[8];
    #pragma unroll
    for (int nt = 0; nt < 8; ++nt) bcol[nt] = bias[(nt << 4) + l15];

    // ---- convert + write A-fragments, slot XOR-swizzled by (m>>2)&7
    #pragma unroll
    for (int i = 0; i < 4; ++i) {
        int q  = (i << 8) + t;
        int cp = q >> 4, mq = q & 15;
        int c0 = cp << 1, m = mq << 2;
        int kk = c0 >> 5, kc2 = (c0 >> 3) & 3, j = c0 & 7;
        const float* a0 = (const float*)&va[2 * i];
        const float* a1 = (const float*)&va[2 * i + 1];
        #pragma unroll
        for (int d = 0; d < 4; ++d) {
            int row  = m + d;
            int slot = ((((row >> 4) << 2) + kk) << 6) + (row & 15) + (kc2 << 4);
            slot ^= (row >> 2) & 7;
            __hip_bfloat162 pk = __float22bfloat162_rn(make_float2(a0[d], a1[d]));
            *(ushort2*)&AO[(slot << 3) + j] = *(ushort2*)&pk;
        }
    }
    __syncthreads();   // A + W ready

    // ---- MFMA: wave wv owns 16 rows x 128 cols, K=128 in 4 steps
    f32x4 acc[8];
    #pragma unroll
    for (int i = 0; i < 8; ++i) acc[i] = (f32x4){0.f, 0.f, 0.f, 0.f};

    #pragma unroll
    for (int kk = 0; kk < 4; ++kk) {
        int aslot = ((((wv << 2) + kk) << 6) + lane) ^ ((((wv << 4) + l15) >> 2) & 7);
        bf16x8 a = *(const bf16x8*)&AO[aslot << 3];
        #pragma unroll
        for (int nt = 0; nt < 8; ++nt) {
            bf16x8 b = *(const bf16x8*)&Wl[((((nt << 2) + kk) << 6) + lane) << 3];
            acc[nt] = __builtin_amdgcn_mfma_f32_16x16x32_bf16(a, b, acc[nt], 0, 0, 0);
        }
    }

    // ---- softmax in place (C/D layout: col=l15+nt*16, row=quad*4+rr)
    float inv[4];
    #pragma unroll
    for (int rr = 0; rr < 4; ++rr) {
        float s = 0.f;
        #pragma unroll
        for (int nt = 0; nt < 8; ++nt) {
            acc[nt][rr] = __expf(acc[nt][rr] + bcol[nt]);
            s += acc[nt][rr];
        }
        s += __shfl_xor(s, 1, 64);
        s += __shfl_xor(s, 2, 64);
        s += __shfl_xor(s, 4, 64);
        s += __shfl_xor(s, 8, 64);
        inv[rr] = 1.0f / s;
    }

    // ---- transpose probs (fp16) into the wave's OWN A region:
    // chunk swizzle g(quad) = ((quad&1)<<2)|(quad&2)
    const int g = ((quad & 1) << 2) | (quad & 2);
    #pragma unroll
    for (int nt = 0; nt < 8; ++nt) {
        int cl = ((nt << 1) + (l15 >> 3)) ^ g;
        #pragma unroll
        for (int rr = 0; rr < 4; ++rr) {
            int row = (wv << 4) + (quad << 2) + rr;
            AO[(row << 7) + (cl << 3) + (l15 & 7)] =
                __half_as_ushort(__float2half_rn(acc[nt][rr] * inv[rr]));
        }
    }
    __syncthreads();   // all 64 rows' probs visible to all waves

    // ---- scatter: wave wv handles bucket entries e = wv, wv+4, ...
    // each entry: uniform 4B metadata load + 256B LDS row read + 512B coalesced store
    const int nb = min(cnt[blockIdx.x], CAP);
    const int* pb = pairs + blockIdx.x * CAP;
    #pragma unroll 2
    for (int e = wv; e < nb; e += 4) {
        int pk  = pb[e];
        int row = pk & 63;
        int k   = pk >> 6;
        int qd  = (row >> 2) & 3;
        int gq  = ((qd & 1) << 2) | (qd & 2);
        int cl  = (lane >> 2) ^ gq;
        __half2 h = *(const __half2*)&AO[(row << 7) + (cl << 3) + ((lane << 1) & 7)];
        float2 f = __half22float2(h);
        *(float2*)&out[((size_t)k << 7) + (lane << 1)] = f;
    }
}

extern "C" void kernel_launch(void* const* d_in, const int* in_sizes, int n_in,
                              void* d_out, int out_size, void* d_ws, size_t ws_size,
                              hipStream_t stream) {
    const float* gc   = (const float*)d_in[0];   // [1,128,512,512] fp32
    const int*   idx  = (const int*)d_in[1];     // [1,131072] int32
    const float* Wc   = (const float*)d_in[2];   // [128,128] fp32
    const float* bias = (const float*)d_in[3];   // [128] fp32
    float* out = (float*)d_out;                  // [131072,128] fp32

    char* ws = (char*)d_ws;
    int*    cnt   = (int*)(ws);                  // 4096 ints (16 KiB)
    int*    pairs = (int*)(ws + 0x10000);        // 4096*192 ints (3 MiB)
    ushort* Wf    = (ushort*)(ws + 0x400000);    // 16384 bf16 (32 KiB)

    prep        <<<dim3(68),       dim3(256), 0, stream>>>(Wc, Wf, (int4*)cnt);
    csr_fill    <<<dim3(KROWS/256),dim3(256), 0, stream>>>(idx, cnt, pairs);
    gemm_scatter<<<dim3(NTILE),    dim3(256), 0, stream>>>(gc, Wf, bias, cnt, pairs, out);
}